// Round 1
// baseline (95.719 us; speedup 1.0000x reference)
//
#include <hip/hip_runtime.h>
#include <hip/hip_bf16.h>

#define N_NODES 100000
#define DEG 16
#define D 128

typedef __bf16 bf16x8 __attribute__((ext_vector_type(8)));
typedef float f32x4 __attribute__((ext_vector_type(4)));

__device__ __forceinline__ ushort f32_to_bf16u(float f) {
  unsigned u = __float_as_uint(f);
  u = (u + 0x7fffu + ((u >> 16) & 1u)) >> 16;
  return (ushort)u;
}

// swizzled element index into a [128][128] ushort LDS tile (XOR bits 3..5 of k with row bits 0..2)
__device__ __forceinline__ int swz(int row, int k) {
  return (row << 7) + (k ^ ((row & 7) << 3));
}

// Kernel 0: W [k][n] f32 -> Wt bf16 transposed [n][k], swizzled (one block)
__global__ void k_convW(const float* __restrict__ W, ushort* __restrict__ Wt) {
  const int t = threadIdx.x;
  for (int j = 0; j < 64; ++j) {
    int pos = (j << 8) + t;            // 0..16383
    int k = pos >> 7, n = pos & 127;
    Wt[swz(n, k)] = f32_to_bf16u(W[pos]);
  }
}

// Kernel 1: Xp = bf16(X @ W).  128-row tile per block, 4 waves, MFMA 16x16x32 bf16.
__global__ __launch_bounds__(256, 2) void k_gemm(const float* __restrict__ X,
                                                 const ushort* __restrict__ Wt,
                                                 ushort* __restrict__ Xp) {
  __shared__ __align__(16) ushort As[128 * 128];
  __shared__ __align__(16) ushort Ws[128 * 128];
  const int tid = threadIdx.x;
  const int row0 = blockIdx.x << 7;

  // linear 32 KB copy of pre-swizzled Wt into LDS
  {
    const uint4* src = (const uint4*)Wt;
    uint4* dst = (uint4*)Ws;
#pragma unroll
    for (int j = 0; j < 8; ++j) dst[(j << 8) + tid] = src[(j << 8) + tid];
  }
  // stage A tile: f32 -> bf16, swizzled
#pragma unroll
  for (int j = 0; j < 16; ++j) {
    int pos = (j << 8) + tid;          // 0..4095 float4 slots
    int r = pos >> 5;                  // tile row
    int c4 = (pos & 31) << 2;          // col, multiple of 4
    int grow = row0 + r;
    float4 v = make_float4(0.f, 0.f, 0.f, 0.f);
    if (grow < N_NODES) v = *(const float4*)(X + grow * D + c4);
    ushort4 b;
    b.x = f32_to_bf16u(v.x); b.y = f32_to_bf16u(v.y);
    b.z = f32_to_bf16u(v.z); b.w = f32_to_bf16u(v.w);
    *(ushort4*)(As + swz(r, c4)) = b;
  }
  __syncthreads();

  const int wave = tid >> 6;
  const int lane = tid & 63;
  const int lhi = lane >> 4;           // 0..3
  const int llo = lane & 15;

  f32x4 acc[2][8];
#pragma unroll
  for (int m = 0; m < 2; ++m)
#pragma unroll
    for (int n = 0; n < 8; ++n)
      acc[m][n] = (f32x4){0.f, 0.f, 0.f, 0.f};

#pragma unroll
  for (int t = 0; t < 4; ++t) {
    const int k0 = (t << 5) + (lhi << 3);
    bf16x8 a[2], b[8];
#pragma unroll
    for (int m = 0; m < 2; ++m) {
      int r = (wave << 5) + (m << 4) + llo;
      a[m] = *(const bf16x8*)(As + swz(r, k0));
    }
#pragma unroll
    for (int n = 0; n < 8; ++n) {
      int cc = (n << 4) + llo;
      b[n] = *(const bf16x8*)(Ws + swz(cc, k0));
    }
#pragma unroll
    for (int m = 0; m < 2; ++m)
#pragma unroll
      for (int n = 0; n < 8; ++n)
        acc[m][n] = __builtin_amdgcn_mfma_f32_16x16x32_bf16(a[m], b[n], acc[m][n], 0, 0, 0);
  }

  // epilogue: C/D layout col=lane&15, row=(lane>>4)*4+reg
#pragma unroll
  for (int m = 0; m < 2; ++m) {
    int rbase = row0 + (wave << 5) + (m << 4) + (lhi << 2);
#pragma unroll
    for (int n = 0; n < 8; ++n) {
      int col = (n << 4) + llo;
#pragma unroll
      for (int r = 0; r < 4; ++r) {
        int grow = rbase + r;
        if (grow < N_NODES) Xp[grow * D + col] = f32_to_bf16u(acc[m][n][r]);
      }
    }
  }
}

// Kernel 2: out[i] = sum_{e in [i*16,(i+1)*16)} Xp[ci[e]]   (one wave per row)
__global__ __launch_bounds__(256) void k_spmm(const ushort* __restrict__ Xp,
                                              const int* __restrict__ ci,
                                              float* __restrict__ out) {
  const int wave = threadIdx.x >> 6;
  const int lane = threadIdx.x & 63;
  const int row = (blockIdx.x << 2) + wave;
  if (row >= N_NODES) return;

  int idx = 0;
  if (lane < DEG) idx = ci[row * DEG + lane];

  float ax = 0.f, ay = 0.f;
#pragma unroll
  for (int e = 0; e < DEG; ++e) {
    int col = __shfl(idx, e);
    unsigned v = *(const unsigned*)(Xp + col * D + (lane << 1));
    ax += __uint_as_float(v << 16);          // low bf16  -> col lane*2
    ay += __uint_as_float(v & 0xffff0000u);  // high bf16 -> col lane*2+1
  }
  *(float2*)(out + row * D + (lane << 1)) = make_float2(ax, ay);
}

extern "C" void kernel_launch(void* const* d_in, const int* in_sizes, int n_in,
                              void* d_out, int out_size, void* d_ws, size_t ws_size,
                              hipStream_t stream) {
  const float* X = (const float*)d_in[0];
  const float* W = (const float*)d_in[1];
  const int* ci = (const int*)d_in[3];

  ushort* Wt = (ushort*)d_ws;                 // 32 KB
  ushort* Xp = (ushort*)d_ws + 128 * 128;     // 25.6 MB bf16 X'
  float* out = (float*)d_out;

  k_convW<<<1, 256, 0, stream>>>(W, Wt);
  k_gemm<<<(N_NODES + 127) / 128, 256, 0, stream>>>(X, Wt, Xp);
  k_spmm<<<N_NODES / 4, 256, 0, stream>>>(Xp, ci, out);
}

// Round 2
// 90.577 us; speedup vs baseline: 1.0568x; 1.0568x over previous
//
#include <hip/hip_runtime.h>
#include <hip/hip_bf16.h>

#define N_NODES 100000
#define DEG 16
#define D 128

typedef __bf16 bf16x8 __attribute__((ext_vector_type(8)));
typedef float f32x4 __attribute__((ext_vector_type(4)));

__device__ __forceinline__ unsigned pk2(float a, float b) {
  union { __bf16 h[2]; unsigned u; } x;
  x.h[0] = (__bf16)a; x.h[1] = (__bf16)b;
  return x.u;
}

// swizzled element index into a [128][128] ushort LDS tile (XOR bits 3..5 of k with row bits 0..2)
__device__ __forceinline__ int swz(int row, int k) {
  return (row << 7) + (k ^ ((row & 7) << 3));
}

// Kernel 0: W [k][n] f32 -> Wt bf16 transposed [n][k], swizzled (one block)
__global__ void k_convW(const float* __restrict__ W, ushort* __restrict__ Wt) {
  const int t = threadIdx.x;
  for (int j = 0; j < 64; ++j) {
    int pos = (j << 8) + t;            // 0..16383
    int k = pos >> 7, n = pos & 127;
    union { __bf16 h; ushort u; } c;
    c.h = (__bf16)W[pos];
    Wt[swz(n, k)] = c.u;
  }
}

// Kernel 1: Xp = bf16(X @ W), rows stored in permuted col order: pos p=llo*8+n <-> col n*16+llo.
// 128-row tile per block, 4 waves, A-fragments loaded direct from global (no A LDS).
__global__ __launch_bounds__(256, 2) void k_gemm(const float* __restrict__ X,
                                                 const ushort* __restrict__ Wt,
                                                 ushort* __restrict__ Xp) {
  __shared__ __align__(16) ushort Ws[128 * 128];
  const int tid = threadIdx.x;
  const int row0 = blockIdx.x << 7;
  const int wave = tid >> 6;
  const int lane = tid & 63;
  const int lhi = lane >> 4;           // 0..3
  const int llo = lane & 15;

  // stage pre-swizzled Wt (32 KB linear copy)
  {
    const uint4* src = (const uint4*)Wt;
    uint4* dst = (uint4*)Ws;
#pragma unroll
    for (int j = 0; j < 8; ++j) dst[(j << 8) + tid] = src[(j << 8) + tid];
  }

  // direct A-fragment loads: lane owns row llo (per m), k-slice lhi*8..+8 (per t)
  float4 xa[2][4][2];
#pragma unroll
  for (int m = 0; m < 2; ++m) {
    int row = row0 + (wave << 5) + (m << 4) + llo;
    const float* rp = X + row * D + (lhi << 3);
    bool ok = row < N_NODES;
#pragma unroll
    for (int t = 0; t < 4; ++t) {
      xa[m][t][0] = ok ? *(const float4*)(rp + (t << 5)) : make_float4(0.f, 0.f, 0.f, 0.f);
      xa[m][t][1] = ok ? *(const float4*)(rp + (t << 5) + 4) : make_float4(0.f, 0.f, 0.f, 0.f);
    }
  }
  __syncthreads();

  f32x4 acc[2][8];
#pragma unroll
  for (int m = 0; m < 2; ++m)
#pragma unroll
    for (int n = 0; n < 8; ++n)
      acc[m][n] = (f32x4){0.f, 0.f, 0.f, 0.f};

#pragma unroll
  for (int t = 0; t < 4; ++t) {
    const int k0 = (t << 5) + (lhi << 3);
    bf16x8 a[2], b[8];
#pragma unroll
    for (int m = 0; m < 2; ++m) {
      float4 p = xa[m][t][0], q = xa[m][t][1];
      bf16x8 v;
      v[0] = (__bf16)p.x; v[1] = (__bf16)p.y; v[2] = (__bf16)p.z; v[3] = (__bf16)p.w;
      v[4] = (__bf16)q.x; v[5] = (__bf16)q.y; v[6] = (__bf16)q.z; v[7] = (__bf16)q.w;
      a[m] = v;
    }
#pragma unroll
    for (int n = 0; n < 8; ++n)
      b[n] = *(const bf16x8*)(Ws + swz((n << 4) + llo, k0));
#pragma unroll
    for (int m = 0; m < 2; ++m)
#pragma unroll
      for (int n = 0; n < 8; ++n)
        acc[m][n] = __builtin_amdgcn_mfma_f32_16x16x32_bf16(a[m], b[n], acc[m][n], 0, 0, 0);
  }

  // epilogue: C/D layout col=llo, row=lhi*4+r. Pack 8 cols (n=0..7) -> uint4 per (m,r).
#pragma unroll
  for (int m = 0; m < 2; ++m) {
#pragma unroll
    for (int r = 0; r < 4; ++r) {
      int row = row0 + (wave << 5) + (m << 4) + (lhi << 2) + r;
      if (row < N_NODES) {
        uint4 v;
        v.x = pk2(acc[m][0][r], acc[m][1][r]);
        v.y = pk2(acc[m][2][r], acc[m][3][r]);
        v.z = pk2(acc[m][4][r], acc[m][5][r]);
        v.w = pk2(acc[m][6][r], acc[m][7][r]);
        *(uint4*)(Xp + row * D + (llo << 3)) = v;
      }
    }
  }
}

// Kernel 2: out[i] = sum_{e} Xp[ci[e]]  (one wave per row; Xp rows are col-permuted)
__global__ __launch_bounds__(256) void k_spmm(const ushort* __restrict__ Xp,
                                              const int* __restrict__ ci,
                                              float* __restrict__ out) {
  const int wave = threadIdx.x >> 6;
  const int lane = threadIdx.x & 63;
  const int row = (blockIdx.x << 2) + wave;
  if (row >= N_NODES) return;

  int idx = 0;
  if (lane < DEG) idx = __builtin_nontemporal_load(ci + row * DEG + lane);

  unsigned v[16];
#pragma unroll
  for (int e = 0; e < DEG; ++e) {
    int col = __shfl(idx, e);
    v[e] = *(const unsigned*)(Xp + col * D + (lane << 1));
  }

  float ax = 0.f, ay = 0.f;
#pragma unroll
  for (int e = 0; e < DEG; ++e) {
    ax += __uint_as_float(v[e] << 16);
    ay += __uint_as_float(v[e] & 0xffff0000u);
  }

  // lane holds permuted positions p=2*lane (->c0) and p=2*lane+1 (->c0+16)
  const int c0 = (((lane << 1) & 7) << 4) + (lane >> 2);
  __builtin_nontemporal_store(ax, out + row * D + c0);
  __builtin_nontemporal_store(ay, out + row * D + c0 + 16);
}

extern "C" void kernel_launch(void* const* d_in, const int* in_sizes, int n_in,
                              void* d_out, int out_size, void* d_ws, size_t ws_size,
                              hipStream_t stream) {
  const float* X = (const float*)d_in[0];
  const float* W = (const float*)d_in[1];
  const int* ci = (const int*)d_in[3];

  ushort* Wt = (ushort*)d_ws;                 // 32 KB
  ushort* Xp = (ushort*)d_ws + 128 * 128;     // 25.6 MB bf16 X' (permuted rows)
  float* out = (float*)d_out;

  k_convW<<<1, 256, 0, stream>>>(W, Wt);
  k_gemm<<<(N_NODES + 127) / 128, 256, 0, stream>>>(X, Wt, Xp);
  k_spmm<<<N_NODES / 4, 256, 0, stream>>>(Xp, ci, out);
}

// Round 3
// 83.446 us; speedup vs baseline: 1.1471x; 1.0855x over previous
//
#include <hip/hip_runtime.h>
#include <hip/hip_bf16.h>

#define N_NODES 100000
#define DEG 16
#define D 128

typedef __bf16 bf16x8 __attribute__((ext_vector_type(8)));
typedef float f32x4 __attribute__((ext_vector_type(4)));

__device__ __forceinline__ unsigned pk2(float a, float b) {
  union { __bf16 h[2]; unsigned u; } x;
  x.h[0] = (__bf16)a; x.h[1] = (__bf16)b;
  return x.u;
}

// swizzled element index into a [128][128] ushort LDS tile (XOR bits 3..5 of k with row bits 0..2)
__device__ __forceinline__ int swz(int row, int k) {
  return (row << 7) + (k ^ ((row & 7) << 3));
}

// Kernel 0: W [k][n] f32 -> Wt bf16 transposed [n][k], swizzled (64 blocks, 1 elem/thread)
__global__ void k_convW(const float* __restrict__ W, ushort* __restrict__ Wt) {
  int pos = (blockIdx.x << 8) + threadIdx.x;   // 0..16383
  int k = pos >> 7, n = pos & 127;
  union { __bf16 h; ushort u; } c;
  c.h = (__bf16)W[pos];
  Wt[swz(n, k)] = c.u;
}

// Kernel 1: Xp = bf16(X @ W), rows stored in permuted col order: pos p=llo*8+n <-> col n*16+llo.
// 128-row tile per block, 4 waves, A-fragments loaded direct from global (no A LDS).
__global__ __launch_bounds__(256, 2) void k_gemm(const float* __restrict__ X,
                                                 const ushort* __restrict__ Wt,
                                                 ushort* __restrict__ Xp) {
  __shared__ __align__(16) ushort Ws[128 * 128];
  const int tid = threadIdx.x;
  const int row0 = blockIdx.x << 7;
  const int wave = tid >> 6;
  const int lane = tid & 63;
  const int lhi = lane >> 4;           // 0..3
  const int llo = lane & 15;

  // stage pre-swizzled Wt (32 KB linear copy)
  {
    const uint4* src = (const uint4*)Wt;
    uint4* dst = (uint4*)Ws;
#pragma unroll
    for (int j = 0; j < 8; ++j) dst[(j << 8) + tid] = src[(j << 8) + tid];
  }

  // direct A-fragment loads: lane owns row llo (per m), k-slice lhi*8..+8 (per t)
  float4 xa[2][4][2];
#pragma unroll
  for (int m = 0; m < 2; ++m) {
    int row = row0 + (wave << 5) + (m << 4) + llo;
    const float* rp = X + row * D + (lhi << 3);
    bool ok = row < N_NODES;
#pragma unroll
    for (int t = 0; t < 4; ++t) {
      xa[m][t][0] = ok ? *(const float4*)(rp + (t << 5)) : make_float4(0.f, 0.f, 0.f, 0.f);
      xa[m][t][1] = ok ? *(const float4*)(rp + (t << 5) + 4) : make_float4(0.f, 0.f, 0.f, 0.f);
    }
  }
  __syncthreads();

  f32x4 acc[2][8];
#pragma unroll
  for (int m = 0; m < 2; ++m)
#pragma unroll
    for (int n = 0; n < 8; ++n)
      acc[m][n] = (f32x4){0.f, 0.f, 0.f, 0.f};

#pragma unroll
  for (int t = 0; t < 4; ++t) {
    const int k0 = (t << 5) + (lhi << 3);
    bf16x8 a[2], b[8];
#pragma unroll
    for (int m = 0; m < 2; ++m) {
      float4 p = xa[m][t][0], q = xa[m][t][1];
      bf16x8 v;
      v[0] = (__bf16)p.x; v[1] = (__bf16)p.y; v[2] = (__bf16)p.z; v[3] = (__bf16)p.w;
      v[4] = (__bf16)q.x; v[5] = (__bf16)q.y; v[6] = (__bf16)q.z; v[7] = (__bf16)q.w;
      a[m] = v;
    }
#pragma unroll
    for (int n = 0; n < 8; ++n)
      b[n] = *(const bf16x8*)(Ws + swz((n << 4) + llo, k0));
#pragma unroll
    for (int m = 0; m < 2; ++m)
#pragma unroll
      for (int n = 0; n < 8; ++n)
        acc[m][n] = __builtin_amdgcn_mfma_f32_16x16x32_bf16(a[m], b[n], acc[m][n], 0, 0, 0);
  }

  // epilogue: C/D layout col=llo, row=lhi*4+r. Pack 8 cols (n=0..7) -> uint4 per (m,r).
#pragma unroll
  for (int m = 0; m < 2; ++m) {
#pragma unroll
    for (int r = 0; r < 4; ++r) {
      int row = row0 + (wave << 5) + (m << 4) + (lhi << 2) + r;
      if (row < N_NODES) {
        uint4 v;
        v.x = pk2(acc[m][0][r], acc[m][1][r]);
        v.y = pk2(acc[m][2][r], acc[m][3][r]);
        v.z = pk2(acc[m][4][r], acc[m][5][r]);
        v.w = pk2(acc[m][6][r], acc[m][7][r]);
        *(uint4*)(Xp + row * D + (llo << 3)) = v;
      }
    }
  }
}

// Kernel 2: out[i] = sum_{e} Xp[ci[e]]  (one wave per row; Xp rows are col-permuted)
// Quarter-wave scheme: group g = lane>>4 handles edges 4g..4g+3; lane j = lane&15
// loads 16 B (positions j*8..j*8+8 = logical cols {n*16+j}). Cross-group reduce
// via shfl_xor(16,32); group-g store covers contiguous cols 32g..32g+31.
__global__ __launch_bounds__(256) void k_spmm(const ushort* __restrict__ Xp,
                                              const int* __restrict__ ci,
                                              float* __restrict__ out) {
  const int wave = threadIdx.x >> 6;
  const int lane = threadIdx.x & 63;
  const int row = (blockIdx.x << 2) + wave;
  if (row >= N_NODES) return;
  const int g = lane >> 4;
  const int j = lane & 15;

  int idx = 0;
  if (lane < DEG) idx = __builtin_nontemporal_load(ci + row * DEG + lane);

  uint4 v[4];
#pragma unroll
  for (int e = 0; e < 4; ++e) {
    int col = __shfl(idx, (g << 2) + e);
    v[e] = *(const uint4*)(Xp + col * D + (j << 3));
  }

  float acc[8];
#pragma unroll
  for (int n = 0; n < 8; ++n) acc[n] = 0.f;
#pragma unroll
  for (int e = 0; e < 4; ++e) {
    acc[0] += __uint_as_float(v[e].x << 16);
    acc[1] += __uint_as_float(v[e].x & 0xffff0000u);
    acc[2] += __uint_as_float(v[e].y << 16);
    acc[3] += __uint_as_float(v[e].y & 0xffff0000u);
    acc[4] += __uint_as_float(v[e].z << 16);
    acc[5] += __uint_as_float(v[e].z & 0xffff0000u);
    acc[6] += __uint_as_float(v[e].w << 16);
    acc[7] += __uint_as_float(v[e].w & 0xffff0000u);
  }

#pragma unroll
  for (int n = 0; n < 8; ++n) {
    acc[n] += __shfl_xor(acc[n], 16);
    acc[n] += __shfl_xor(acc[n], 32);
  }

  // lane (g,j): acc[n] holds col n*16+j; store acc[2g]->col 32g+j, acc[2g+1]->col 32g+16+j
  float* op = out + row * D + (g << 5) + j;
  __builtin_nontemporal_store(acc[(g << 1)], op);
  __builtin_nontemporal_store(acc[(g << 1) + 1], op + 16);
}

extern "C" void kernel_launch(void* const* d_in, const int* in_sizes, int n_in,
                              void* d_out, int out_size, void* d_ws, size_t ws_size,
                              hipStream_t stream) {
  const float* X = (const float*)d_in[0];
  const float* W = (const float*)d_in[1];
  const int* ci = (const int*)d_in[3];

  ushort* Wt = (ushort*)d_ws;                 // 32 KB
  ushort* Xp = (ushort*)d_ws + 128 * 128;     // 25.6 MB bf16 X' (permuted rows)
  float* out = (float*)d_out;

  k_convW<<<64, 256, 0, stream>>>(W, Wt);
  k_gemm<<<(N_NODES + 127) / 128, 256, 0, stream>>>(X, Wt, Xp);
  k_spmm<<<N_NODES / 4, 256, 0, stream>>>(Xp, ci, out);
}